// Round 1
// baseline (59.623 us; speedup 1.0000x reference)
//
#include <hip/hip_runtime.h>

#define HWX 65536
#define NQ 128      // N (queries)
#define KT 64       // K (targets)
#define CC 134      // classes
#define BB 2        // batch
#define SL 64       // k-slices per (b, nt)
#define NT 2        // row strips of 64
#define SLICE (HWX / SL)       // 1024
#define CHUNKS (SLICE / 32)    // 32
#define EPSI 1e-5f

typedef __attribute__((ext_vector_type(4))) float f32x4;
typedef __attribute__((ext_vector_type(8))) short bf16x8;

static __device__ __forceinline__ unsigned int cvtpk(float lo, float hi) {
  unsigned int r;
  asm("v_cvt_pk_bf16_f32 %0, %1, %2" : "=v"(r) : "v"(lo), "v"(hi));
  return r;
}

// ---------------- int64-vs-int32 detection for target_class ----------------
// If data is genuine int64 (values 0..133), every hi-word is 0. If it is
// int32, the "hi-words" are odd-index class values (P(all zero) ~ (1/134)^64).
// Only touches the first 512 B, valid in both layouts.
__global__ void hm_detect(const unsigned int* __restrict__ t,
                          unsigned int* __restrict__ flag) {
  unsigned int w = t[threadIdx.x * 2 + 1];
  unsigned long long any = __ballot(w != 0u);
  if (threadIdx.x == 0) *flag = (any != 0ull) ? 1u : 0u;  // 1 => int32 data
}

// ---------------- stage 1: split-K MFMA partial intersections ---------------
// grid = BB*NT*SL blocks (256), 512 threads (8 waves: wr 0..3 x wc 0..1).
// Wave computes rows [nt*64+wr*16, +16) x cols [wc*32, +32) over a 1024-wide
// k-slice, fragments loaded straight from global, fp32->bf16 in registers.
template <bool ATOMIC>
__global__ __launch_bounds__(512)
void hm_stage1(const float* __restrict__ in_mask, const float* __restrict__ tg_mask,
               float* __restrict__ Ipart, float* __restrict__ RSin,
               float* __restrict__ RStg) {
  const int blk = blockIdx.x;
  const int s  = blk & (SL - 1);
  const int nt = (blk >> 6) & (NT - 1);
  const int b  = blk >> 7;
  const int wave = threadIdx.x >> 6;
  const int lane = threadIdx.x & 63;
  const int wr = wave >> 1;
  const int wc = wave & 1;
  const int l16 = lane & 15;
  const int lg  = lane >> 4;

  const size_t kbase = (size_t)s * SLICE + lg * 8;
  const float* A  = in_mask + ((size_t)b * NQ + nt * 64 + wr * 16 + l16) * HWX + kbase;
  const float* B0 = tg_mask + ((size_t)b * KT + wc * 32 + l16) * HWX + kbase;
  const float* B1 = B0 + (size_t)16 * HWX;

  f32x4 acc0 = {0.f, 0.f, 0.f, 0.f};
  f32x4 acc1 = {0.f, 0.f, 0.f, 0.f};
  float sA = 0.f, s0 = 0.f, s1 = 0.f;
  const bool doA = (wc == 0);             // each row summed exactly once
  const bool doB = (nt == 0) && (wr == 0); // each target row summed exactly once

  #pragma unroll 4
  for (int c = 0; c < CHUNKS; ++c) {
    const int o = c * 32;
    f32x4 a0 = *(const f32x4*)(A + o);
    f32x4 a1 = *(const f32x4*)(A + o + 4);
    f32x4 p0 = *(const f32x4*)(B0 + o);
    f32x4 p1 = *(const f32x4*)(B0 + o + 4);
    f32x4 q0 = *(const f32x4*)(B1 + o);
    f32x4 q1 = *(const f32x4*)(B1 + o + 4);

    if (doA) sA += a0.x + a0.y + a0.z + a0.w + a1.x + a1.y + a1.z + a1.w;
    if (doB) {
      s0 += p0.x + p0.y + p0.z + p0.w + p1.x + p1.y + p1.z + p1.w;
      s1 += q0.x + q0.y + q0.z + q0.w + q1.x + q1.y + q1.z + q1.w;
    }

    union { unsigned int u[4]; bf16x8 v; } fa, fb0, fb1;
    fa.u[0]  = cvtpk(a0.x, a0.y); fa.u[1]  = cvtpk(a0.z, a0.w);
    fa.u[2]  = cvtpk(a1.x, a1.y); fa.u[3]  = cvtpk(a1.z, a1.w);
    fb0.u[0] = cvtpk(p0.x, p0.y); fb0.u[1] = cvtpk(p0.z, p0.w);
    fb0.u[2] = cvtpk(p1.x, p1.y); fb0.u[3] = cvtpk(p1.z, p1.w);
    fb1.u[0] = cvtpk(q0.x, q0.y); fb1.u[1] = cvtpk(q0.z, q0.w);
    fb1.u[2] = cvtpk(q1.x, q1.y); fb1.u[3] = cvtpk(q1.z, q1.w);

    acc0 = __builtin_amdgcn_mfma_f32_16x16x32_bf16(fa.v, fb0.v, acc0, 0, 0, 0);
    acc1 = __builtin_amdgcn_mfma_f32_16x16x32_bf16(fa.v, fb1.v, acc1, 0, 0, 0);
  }

  // C/D layout (verified m89/m91): col = lane&15, row = (lane>>4)*4 + reg
  const int rb = wr * 16 + lg * 4;
  const int cb = wc * 32 + l16;

  if (!ATOMIC) {
    float* tile = Ipart + (size_t)blk * (64 * 64);
    #pragma unroll
    for (int j = 0; j < 4; ++j) {
      tile[(rb + j) * 64 + cb]      = acc0[j];
      tile[(rb + j) * 64 + cb + 16] = acc1[j];
    }
  } else {
    float* dst = Ipart + ((size_t)b * NQ + nt * 64) * KT;
    #pragma unroll
    for (int j = 0; j < 4; ++j) {
      atomicAdd(&dst[(rb + j) * KT + cb],      acc0[j]);
      atomicAdd(&dst[(rb + j) * KT + cb + 16], acc1[j]);
    }
  }

  sA += __shfl_xor(sA, 16); sA += __shfl_xor(sA, 32);
  s0 += __shfl_xor(s0, 16); s0 += __shfl_xor(s0, 32);
  s1 += __shfl_xor(s1, 16); s1 += __shfl_xor(s1, 32);

  if (!ATOMIC) {
    if (doA && lane < 16)
      RSin[((size_t)b * SL + s) * NQ + nt * 64 + wr * 16 + lane] = sA;
    if (doB && lane < 16) {
      RStg[((size_t)b * SL + s) * KT + wc * 32 + lane]      = s0;
      RStg[((size_t)b * SL + s) * KT + wc * 32 + 16 + lane] = s1;
    }
  } else {
    if (doA && lane < 16) atomicAdd(&RSin[b * NQ + nt * 64 + wr * 16 + lane], sA);
    if (doB && lane < 16) {
      atomicAdd(&RStg[b * KT + wc * 32 + lane],      s0);
      atomicAdd(&RStg[b * KT + wc * 32 + 16 + lane], s1);
    }
  }
}

// ---------------- stage 2 (partial mode): reduce + dice + class gather ------
__global__ __launch_bounds__(256)
void hm_stage2(const float* __restrict__ cprob, const void* __restrict__ tcls,
               const unsigned int* __restrict__ flag,
               const float* __restrict__ Ipart, const float* __restrict__ RSin,
               const float* __restrict__ RStg, float* __restrict__ out) {
  const int idx = blockIdx.x * 256 + threadIdx.x;
  const int k = idx & 63;
  const int n = (idx >> 6) & 127;
  const int b = idx >> 13;
  const int nt = n >> 6, nl = n & 63;
  const float* ip = Ipart + ((size_t)((b * 2 + nt) * 64)) * 4096 + nl * 64 + k;
  const float* ri = RSin + (size_t)b * SL * NQ + n;
  const float* rt = RStg + (size_t)b * SL * KT + k;
  float I = 0.f, ra = 0.f, rg = 0.f;
  #pragma unroll 8
  for (int s = 0; s < SL; ++s) {
    I  += ip[(size_t)s * 4096];
    ra += ri[s * NQ];
    rg += rt[s * KT];
  }
  int tc;
  if (*flag) tc = ((const int*)tcls)[b * KT + k];
  else       tc = (int)((const long long*)tcls)[b * KT + k];
  const float c = cprob[((size_t)b * NQ + n) * CC + tc];
  out[idx] = c * (2.f * I + EPSI) / (ra + rg + EPSI);
}

// ---------------- stage 2 (atomic fallback mode) ----------------------------
__global__ __launch_bounds__(256)
void hm_stage2_direct(const float* __restrict__ cprob, const void* __restrict__ tcls,
                      const unsigned int* __restrict__ flag,
                      const float* __restrict__ Iacc, const float* __restrict__ RSin,
                      const float* __restrict__ RStg, float* __restrict__ out) {
  const int idx = blockIdx.x * 256 + threadIdx.x;
  const int k = idx & 63;
  const int n = (idx >> 6) & 127;
  const int b = idx >> 13;
  const float I  = Iacc[idx];
  const float ra = RSin[b * NQ + n];
  const float rg = RStg[b * KT + k];
  int tc;
  if (*flag) tc = ((const int*)tcls)[b * KT + k];
  else       tc = (int)((const long long*)tcls)[b * KT + k];
  const float c = cprob[((size_t)b * NQ + n) * CC + tc];
  out[idx] = c * (2.f * I + EPSI) / (ra + rg + EPSI);
}

__global__ void hm_zero(float* __restrict__ p, int n) {
  int i = blockIdx.x * blockDim.x + threadIdx.x;
  if (i < n) p[i] = 0.f;
}

extern "C" void kernel_launch(void* const* d_in, const int* in_sizes, int n_in,
                              void* d_out, int out_size, void* d_ws, size_t ws_size,
                              hipStream_t stream) {
  const float* cprob = (const float*)d_in[0];   // (2,128,134) f32
  const float* imask = (const float*)d_in[1];   // (2,128,65536) f32
  const float* tmask = (const float*)d_in[2];   // (2,64,65536) f32
  const void*  tcls  = d_in[3];                 // (2,64) int64 (or int32)
  float* out = (float*)d_out;                   // (2,128,64) f32

  const size_t ipart_f = (size_t)BB * NT * SL * 64 * 64;   // 1,048,576 floats
  const size_t rsin_f  = (size_t)BB * SL * NQ;             // 16,384
  const size_t rstg_f  = (size_t)BB * SL * KT;             // 8,192
  const size_t needA   = (ipart_f + rsin_f + rstg_f + 1) * sizeof(float);

  char* ws = (char*)d_ws;
  if (ws_size >= needA) {
    // deterministic partial-buffer mode (no atomics, no zero-init needed)
    float* Ipart = (float*)ws;
    float* RSin  = Ipart + ipart_f;
    float* RStg  = RSin + rsin_f;
    unsigned int* flag = (unsigned int*)(RStg + rstg_f);
    hm_detect<<<1, 64, 0, stream>>>((const unsigned int*)tcls, flag);
    hm_stage1<false><<<BB * NT * SL, 512, 0, stream>>>(imask, tmask, Ipart, RSin, RStg);
    hm_stage2<<<(BB * NQ * KT) / 256, 256, 0, stream>>>(cprob, tcls, flag, Ipart, RSin, RStg, out);
  } else {
    // small-scratch atomic fallback (~67 KB)
    float* Iacc = (float*)ws;                     // 16384 floats
    float* RSin = Iacc + (size_t)BB * NQ * KT;    // 256
    float* RStg = RSin + BB * NQ;                 // 128
    unsigned int* flag = (unsigned int*)(RStg + BB * KT);
    const int zn = BB * NQ * KT + BB * NQ + BB * KT;
    hm_zero<<<(zn + 255) / 256, 256, 0, stream>>>(Iacc, zn);
    hm_detect<<<1, 64, 0, stream>>>((const unsigned int*)tcls, flag);
    hm_stage1<true><<<BB * NT * SL, 512, 0, stream>>>(imask, tmask, Iacc, RSin, RStg);
    hm_stage2_direct<<<(BB * NQ * KT) / 256, 256, 0, stream>>>(cprob, tcls, flag, Iacc, RSin, RStg, out);
  }
}

// Round 2
// 58.690 us; speedup vs baseline: 1.0159x; 1.0159x over previous
//
#include <hip/hip_runtime.h>

#define HWX 65536
#define NQ 128      // N (queries)
#define KT 64       // K (targets)
#define CC 134      // classes
#define BB 2        // batch
#define NT 2        // row strips of 64
#define EPSI 1e-5f

typedef __attribute__((ext_vector_type(4))) float f32x4;
typedef __attribute__((ext_vector_type(8))) short bf16x8;

static __device__ __forceinline__ unsigned int cvtpk(float lo, float hi) {
  unsigned int r;
  asm("v_cvt_pk_bf16_f32 %0, %1, %2" : "=v"(r) : "v"(lo), "v"(hi));
  return r;
}

// ---------------- int64-vs-int32 detection (atomic-fallback path only) ------
__global__ void hm_detect(const unsigned int* __restrict__ t,
                          unsigned int* __restrict__ flag) {
  unsigned int w = t[threadIdx.x * 2 + 1];
  unsigned long long any = __ballot(w != 0u);
  if (threadIdx.x == 0) *flag = (any != 0ull) ? 1u : 0u;  // 1 => int32 data
}

// ---------------- stage 1: split-K MFMA partial intersections ---------------
// grid = BB*NT*SLN blocks, 512 threads (8 waves: wr 0..3 x wc 0..1).
// Wave computes rows [nt*64+wr*16,+16) x cols [wc*32,+32) over a HWX/SLN-wide
// k-slice; fragments loaded straight from global, fp32->bf16 in registers.
// SLN=256 -> 1024 blocks -> 4 blocks/CU -> 32 waves/CU (full occupancy).
template <int SLN, bool ATOMIC>
__global__ __launch_bounds__(512, 8)
void hm_stage1(const float* __restrict__ in_mask, const float* __restrict__ tg_mask,
               float* __restrict__ Ipart, float* __restrict__ RSin,
               float* __restrict__ RStg) {
  constexpr int SLICE_N = HWX / SLN;
  constexpr int CH = SLICE_N / 32;
  const int blk = blockIdx.x;
  const int s  = blk % SLN;
  const int nt = (blk / SLN) % NT;
  const int b  = blk / (SLN * NT);
  const int wave = threadIdx.x >> 6;
  const int lane = threadIdx.x & 63;
  const int wr = wave >> 1;
  const int wc = wave & 1;
  const int l16 = lane & 15;
  const int lg  = lane >> 4;

  const size_t kbase = (size_t)s * SLICE_N + lg * 8;
  const float* A  = in_mask + ((size_t)b * NQ + nt * 64 + wr * 16 + l16) * HWX + kbase;
  const float* B0 = tg_mask + ((size_t)b * KT + wc * 32 + l16) * HWX + kbase;
  const float* B1 = B0 + (size_t)16 * HWX;

  f32x4 acc0 = {0.f, 0.f, 0.f, 0.f};
  f32x4 acc1 = {0.f, 0.f, 0.f, 0.f};
  float sA = 0.f, s0 = 0.f, s1 = 0.f;
  const bool doA = (wc == 0);              // each input row summed exactly once
  const bool doB = (nt == 0) && (wr == 0); // each target row summed exactly once

  #pragma unroll 4
  for (int c = 0; c < CH; ++c) {
    const int o = c * 32;
    f32x4 a0 = *(const f32x4*)(A + o);
    f32x4 a1 = *(const f32x4*)(A + o + 4);
    f32x4 p0 = *(const f32x4*)(B0 + o);
    f32x4 p1 = *(const f32x4*)(B0 + o + 4);
    f32x4 q0 = *(const f32x4*)(B1 + o);
    f32x4 q1 = *(const f32x4*)(B1 + o + 4);

    if (doA) sA += a0.x + a0.y + a0.z + a0.w + a1.x + a1.y + a1.z + a1.w;
    if (doB) {
      s0 += p0.x + p0.y + p0.z + p0.w + p1.x + p1.y + p1.z + p1.w;
      s1 += q0.x + q0.y + q0.z + q0.w + q1.x + q1.y + q1.z + q1.w;
    }

    union { unsigned int u[4]; bf16x8 v; } fa, fb0, fb1;
    fa.u[0]  = cvtpk(a0.x, a0.y); fa.u[1]  = cvtpk(a0.z, a0.w);
    fa.u[2]  = cvtpk(a1.x, a1.y); fa.u[3]  = cvtpk(a1.z, a1.w);
    fb0.u[0] = cvtpk(p0.x, p0.y); fb0.u[1] = cvtpk(p0.z, p0.w);
    fb0.u[2] = cvtpk(p1.x, p1.y); fb0.u[3] = cvtpk(p1.z, p1.w);
    fb1.u[0] = cvtpk(q0.x, q0.y); fb1.u[1] = cvtpk(q0.z, q0.w);
    fb1.u[2] = cvtpk(q1.x, q1.y); fb1.u[3] = cvtpk(q1.z, q1.w);

    acc0 = __builtin_amdgcn_mfma_f32_16x16x32_bf16(fa.v, fb0.v, acc0, 0, 0, 0);
    acc1 = __builtin_amdgcn_mfma_f32_16x16x32_bf16(fa.v, fb1.v, acc1, 0, 0, 0);
  }

  // C/D layout (verified m89/m91): col = lane&15, row = (lane>>4)*4 + reg
  const int rb = wr * 16 + lg * 4;
  const int cb = wc * 32 + l16;

  if (!ATOMIC) {
    float* tile = Ipart + (size_t)blk * (64 * 64);
    #pragma unroll
    for (int j = 0; j < 4; ++j) {
      tile[(rb + j) * 64 + cb]      = acc0[j];
      tile[(rb + j) * 64 + cb + 16] = acc1[j];
    }
  } else {
    float* dst = Ipart + ((size_t)b * NQ + nt * 64) * KT;
    #pragma unroll
    for (int j = 0; j < 4; ++j) {
      atomicAdd(&dst[(rb + j) * KT + cb],      acc0[j]);
      atomicAdd(&dst[(rb + j) * KT + cb + 16], acc1[j]);
    }
  }

  sA += __shfl_xor(sA, 16); sA += __shfl_xor(sA, 32);
  s0 += __shfl_xor(s0, 16); s0 += __shfl_xor(s0, 32);
  s1 += __shfl_xor(s1, 16); s1 += __shfl_xor(s1, 32);

  if (!ATOMIC) {
    if (doA && lane < 16)
      RSin[((size_t)b * SLN + s) * NQ + nt * 64 + wr * 16 + lane] = sA;
    if (doB && lane < 16) {
      RStg[((size_t)b * SLN + s) * KT + wc * 32 + lane]      = s0;
      RStg[((size_t)b * SLN + s) * KT + wc * 32 + 16 + lane] = s1;
    }
  } else {
    if (doA && lane < 16) atomicAdd(&RSin[b * NQ + nt * 64 + wr * 16 + lane], sA);
    if (doB && lane < 16) {
      atomicAdd(&RStg[b * KT + wc * 32 + lane],      s0);
      atomicAdd(&RStg[b * KT + wc * 32 + 16 + lane], s1);
    }
  }
}

// ---------------- stage 2 (partial mode): reduce + dice + class gather ------
// One block per (b, n): 256 blocks, 256 threads. Threads split the SLN slices
// 4 ways (sq = tid>>6), k = tid&63; LDS combine; wave 0 writes 64 outputs.
// int64-vs-int32 detection folded in (wave 0 ballots the hi-words).
template <int SLN>
__global__ __launch_bounds__(256)
void hm_stage2(const float* __restrict__ cprob, const void* __restrict__ tcls,
               const float* __restrict__ Ipart, const float* __restrict__ RSin,
               const float* __restrict__ RStg, float* __restrict__ out) {
  const int bn = blockIdx.x;            // b*NQ + n
  const int b  = bn / NQ;
  const int n  = bn % NQ;
  const int nt = n >> 6, nl = n & 63;
  const int k  = threadIdx.x & 63;
  const int sq = threadIdx.x >> 6;      // 0..3
  constexpr int SPT = SLN / 4;

  const float* ip = Ipart + ((size_t)(b * NT + nt) * SLN) * 4096 + nl * 64 + k;
  float I = 0.f, ra = 0.f, rg = 0.f;
  #pragma unroll 4
  for (int ss = 0; ss < SPT; ++ss) {
    const int s = sq * SPT + ss;
    I  += ip[(size_t)s * 4096];
    ra += RSin[((size_t)b * SLN + s) * NQ + n];
    rg += RStg[((size_t)b * SLN + s) * KT + k];
  }

  __shared__ float lI[4][64];
  __shared__ float lG[4][64];
  __shared__ float lR[4];
  lI[sq][k] = I;
  lG[sq][k] = rg;
  if (k == 0) lR[sq] = ra;
  __syncthreads();

  if (sq == 0) {
    I  = lI[0][k] + lI[1][k] + lI[2][k] + lI[3][k];
    rg = lG[0][k] + lG[1][k] + lG[2][k] + lG[3][k];
    ra = lR[0] + lR[1] + lR[2] + lR[3];
    // detect int64 vs int32 layout of target_class (first 64 hi-words)
    const unsigned int hi = ((const unsigned int*)tcls)[k * 2 + 1];
    const bool int32_mode = (__ballot(hi != 0u) != 0ull);
    int tc;
    if (int32_mode) tc = ((const int*)tcls)[b * KT + k];
    else            tc = (int)((const long long*)tcls)[b * KT + k];
    const float c = cprob[((size_t)b * NQ + n) * CC + tc];
    out[(size_t)bn * KT + k] = c * (2.f * I + EPSI) / (ra + rg + EPSI);
  }
}

// ---------------- stage 2 (atomic fallback mode) ----------------------------
__global__ __launch_bounds__(256)
void hm_stage2_direct(const float* __restrict__ cprob, const void* __restrict__ tcls,
                      const unsigned int* __restrict__ flag,
                      const float* __restrict__ Iacc, const float* __restrict__ RSin,
                      const float* __restrict__ RStg, float* __restrict__ out) {
  const int idx = blockIdx.x * 256 + threadIdx.x;
  const int k = idx & 63;
  const int n = (idx >> 6) & 127;
  const int b = idx >> 13;
  const float I  = Iacc[idx];
  const float ra = RSin[b * NQ + n];
  const float rg = RStg[b * KT + k];
  int tc;
  if (*flag) tc = ((const int*)tcls)[b * KT + k];
  else       tc = (int)((const long long*)tcls)[b * KT + k];
  const float c = cprob[((size_t)b * NQ + n) * CC + tc];
  out[idx] = c * (2.f * I + EPSI) / (ra + rg + EPSI);
}

__global__ void hm_zero(float* __restrict__ p, int n) {
  int i = blockIdx.x * blockDim.x + threadIdx.x;
  if (i < n) p[i] = 0.f;
}

static inline size_t need_bytes(int sln) {
  return ((size_t)BB * NT * sln * 64 * 64 +  // Ipart
          (size_t)BB * sln * NQ +            // RSin
          (size_t)BB * sln * KT) * 4;        // RStg
}

extern "C" void kernel_launch(void* const* d_in, const int* in_sizes, int n_in,
                              void* d_out, int out_size, void* d_ws, size_t ws_size,
                              hipStream_t stream) {
  const float* cprob = (const float*)d_in[0];   // (2,128,134) f32
  const float* imask = (const float*)d_in[1];   // (2,128,65536) f32
  const float* tmask = (const float*)d_in[2];   // (2,64,65536) f32
  const void*  tcls  = d_in[3];                 // (2,64) int64 (or int32)
  float* out = (float*)d_out;                   // (2,128,64) f32

  char* ws = (char*)d_ws;
  if (ws_size >= need_bytes(256)) {
    constexpr int SLN = 256;
    float* Ipart = (float*)ws;
    float* RSin  = Ipart + (size_t)BB * NT * SLN * 64 * 64;
    float* RStg  = RSin + (size_t)BB * SLN * NQ;
    hm_stage1<SLN, false><<<BB * NT * SLN, 512, 0, stream>>>(imask, tmask, Ipart, RSin, RStg);
    hm_stage2<SLN><<<BB * NQ, 256, 0, stream>>>(cprob, tcls, Ipart, RSin, RStg, out);
  } else if (ws_size >= need_bytes(64)) {
    constexpr int SLN = 64;
    float* Ipart = (float*)ws;
    float* RSin  = Ipart + (size_t)BB * NT * SLN * 64 * 64;
    float* RStg  = RSin + (size_t)BB * SLN * NQ;
    hm_stage1<SLN, false><<<BB * NT * SLN, 512, 0, stream>>>(imask, tmask, Ipart, RSin, RStg);
    hm_stage2<SLN><<<BB * NQ, 256, 0, stream>>>(cprob, tcls, Ipart, RSin, RStg, out);
  } else {
    // small-scratch atomic fallback (~67 KB)
    float* Iacc = (float*)ws;                     // 16384 floats
    float* RSin = Iacc + (size_t)BB * NQ * KT;    // 256
    float* RStg = RSin + BB * NQ;                 // 128
    unsigned int* flag = (unsigned int*)(RStg + BB * KT);
    const int zn = BB * NQ * KT + BB * NQ + BB * KT;
    hm_zero<<<(zn + 255) / 256, 256, 0, stream>>>(Iacc, zn);
    hm_detect<<<1, 64, 0, stream>>>((const unsigned int*)tcls, flag);
    hm_stage1<64, true><<<BB * NT * 64, 512, 0, stream>>>(imask, tmask, Iacc, RSin, RStg);
    hm_stage2_direct<<<(BB * NQ * KT) / 256, 256, 0, stream>>>(cprob, tcls, flag, Iacc, RSin, RStg, out);
  }
}

// Round 3
// 27.580 us; speedup vs baseline: 2.1618x; 2.1280x over previous
//
#include <hip/hip_runtime.h>

#define HWX 65536
#define NQ 128      // N (queries)
#define KT 64       // K (targets)
#define CC 134      // classes
#define BB 2        // batch
#define NW 128      // k-windows
#define WIN 512     // floats per window
#define SUB 128     // floats per sub-slice
#define NSUB 4      // sub-slices per window
#define EPSI 1e-5f

typedef __attribute__((ext_vector_type(4))) float f32x4;
typedef __attribute__((ext_vector_type(8))) short bf16x8;
typedef __attribute__((ext_vector_type(4))) unsigned int u32x4;

static __device__ __forceinline__ unsigned int cvtpk(float lo, float hi) {
  unsigned int r;
  asm("v_cvt_pk_bf16_f32 %0, %1, %2" : "=v"(r) : "v"(lo), "v"(hi));
  return r;
}

// ---------------- int64-vs-int32 detection (atomic-fallback path only) ------
__global__ void hm_detect(const unsigned int* __restrict__ t,
                          unsigned int* __restrict__ flag) {
  unsigned int w = t[threadIdx.x * 2 + 1];
  unsigned long long any = __ballot(w != 0u);
  if (threadIdx.x == 0) *flag = (any != 0ull) ? 1u : 0u;  // 1 => int32 data
}

// ---------------- stage 1: LDS-staged MFMA over one 512-wide k-window -------
// grid = BB*NW = 256 blocks (1/CU), 512 threads (8 waves).
// Per sub-slice (128 k): stage A(128x128)+B(64x128) fp32->bf16 into swizzled
// LDS with fully-coalesced 1KB/wave global loads; each wave then computes its
// 16-row strip vs all 64 target cols (4 MFMA frags) from LDS. Double-buffered
// (96 KB), T14 schedule: issue loads(t+1) -> compute(t) -> cvt+write(t+1).
template <bool ATOMIC>
__global__ __launch_bounds__(512)
void hm_stage1(const float* __restrict__ in_mask, const float* __restrict__ tg_mask,
               float* __restrict__ Ipart, float* __restrict__ RSin,
               float* __restrict__ RStg) {
  const int w = blockIdx.x & (NW - 1);
  const int b = blockIdx.x >> 7;
  const int tid = threadIdx.x;
  const int lane = tid & 63;
  const int wv = tid >> 6;            // wave 0..7
  const int srow = tid >> 4;          // staging row group 0..31
  const int scolb = (tid & 15) * 16;  // staging byte col (8 bf16)
  const int l16 = lane & 15;
  const int lg = lane >> 4;

  __shared__ unsigned short lA[2][128 * 128];  // 32 KB x2, XOR-swizzled bf16
  __shared__ unsigned short lB[2][64 * 128];   // 16 KB x2

  const float* Ab = in_mask + (size_t)b * NQ * HWX + (size_t)w * WIN;
  const float* Bb = tg_mask + (size_t)b * KT * HWX + (size_t)w * WIN;

  f32x4 la[8], lb[4];
  f32x4 acc[4];
  #pragma unroll
  for (int i = 0; i < 4; ++i) acc[i] = f32x4{0.f, 0.f, 0.f, 0.f};
  float rsA[4] = {0.f, 0.f, 0.f, 0.f};
  float rsB[2] = {0.f, 0.f};

  auto ISSUE = [&](int t) {
    #pragma unroll
    for (int it = 0; it < 4; ++it) {
      const float* p = Ab + (size_t)(it * 32 + srow) * HWX + t * SUB + (tid & 15) * 8;
      la[it * 2]     = *(const f32x4*)p;
      la[it * 2 + 1] = *(const f32x4*)(p + 4);
    }
    #pragma unroll
    for (int it = 0; it < 2; ++it) {
      const float* p = Bb + (size_t)(it * 32 + srow) * HWX + t * SUB + (tid & 15) * 8;
      lb[it * 2]     = *(const f32x4*)p;
      lb[it * 2 + 1] = *(const f32x4*)(p + 4);
    }
  };

  auto CVTW = [&](int buf) {
    char* A8 = (char*)lA[buf];
    char* B8 = (char*)lB[buf];
    #pragma unroll
    for (int it = 0; it < 4; ++it) {
      f32x4 x = la[it * 2], y = la[it * 2 + 1];
      rsA[it] += (x.x + x.y) + (x.z + x.w) + (y.x + y.y) + (y.z + y.w);
      u32x4 v;
      v.x = cvtpk(x.x, x.y); v.y = cvtpk(x.z, x.w);
      v.z = cvtpk(y.x, y.y); v.w = cvtpk(y.z, y.w);
      const int row = it * 32 + srow;
      *(u32x4*)(A8 + ((row * 256 + scolb) ^ ((row & 7) << 4))) = v;
    }
    #pragma unroll
    for (int it = 0; it < 2; ++it) {
      f32x4 x = lb[it * 2], y = lb[it * 2 + 1];
      rsB[it] += (x.x + x.y) + (x.z + x.w) + (y.x + y.y) + (y.z + y.w);
      u32x4 v;
      v.x = cvtpk(x.x, x.y); v.y = cvtpk(x.z, x.w);
      v.z = cvtpk(y.x, y.y); v.w = cvtpk(y.z, y.w);
      const int row = it * 32 + srow;
      *(u32x4*)(B8 + ((row * 256 + scolb) ^ ((row & 7) << 4))) = v;
    }
  };

  auto COMP = [&](int buf) {
    const char* A8 = (const char*)lA[buf];
    const char* B8 = (const char*)lB[buf];
    const int arow = wv * 16 + l16;
    const int sw = (l16 & 7) << 4;
    #pragma unroll
    for (int s = 0; s < 4; ++s) {
      bf16x8 fa = *(const bf16x8*)(A8 + ((arow * 256 + s * 64 + lg * 16) ^ sw));
      #pragma unroll
      for (int cf = 0; cf < 4; ++cf) {
        const int brow = cf * 16 + l16;
        bf16x8 fb = *(const bf16x8*)(B8 + ((brow * 256 + s * 64 + lg * 16) ^ sw));
        acc[cf] = __builtin_amdgcn_mfma_f32_16x16x32_bf16(fa, fb, acc[cf], 0, 0, 0);
      }
    }
  };

  ISSUE(0);
  CVTW(0);
  __syncthreads();
  #pragma unroll
  for (int t = 0; t < NSUB; ++t) {
    if (t + 1 < NSUB) ISSUE(t + 1);
    COMP(t & 1);
    if (t + 1 < NSUB) {
      CVTW((t + 1) & 1);
      __syncthreads();
    }
  }

  // ---- write intersections (C layout: col = lane&15, row = (lane>>4)*4+j) --
  #pragma unroll
  for (int cf = 0; cf < 4; ++cf) {
    #pragma unroll
    for (int j = 0; j < 4; ++j) {
      const int row = wv * 16 + lg * 4 + j;
      const int col = cf * 16 + l16;
      if (!ATOMIC)
        Ipart[((size_t)(b * NW + w) * NQ + row) * KT + col] = acc[cf][j];
      else
        atomicAdd(&Ipart[((size_t)b * NQ + row) * KT + col], acc[cf][j]);
    }
  }

  // ---- rowsums: reduce across the 16 threads sharing each staged row -------
  #pragma unroll
  for (int it = 0; it < 4; ++it) {
    float v = rsA[it];
    v += __shfl_xor(v, 1); v += __shfl_xor(v, 2);
    v += __shfl_xor(v, 4); v += __shfl_xor(v, 8);
    rsA[it] = v;
  }
  #pragma unroll
  for (int it = 0; it < 2; ++it) {
    float v = rsB[it];
    v += __shfl_xor(v, 1); v += __shfl_xor(v, 2);
    v += __shfl_xor(v, 4); v += __shfl_xor(v, 8);
    rsB[it] = v;
  }
  if ((tid & 15) == 0) {
    if (!ATOMIC) {
      #pragma unroll
      for (int it = 0; it < 4; ++it)
        RSin[(size_t)(b * NW + w) * NQ + it * 32 + srow] = rsA[it];
      #pragma unroll
      for (int it = 0; it < 2; ++it)
        RStg[(size_t)(b * NW + w) * KT + it * 32 + srow] = rsB[it];
    } else {
      #pragma unroll
      for (int it = 0; it < 4; ++it)
        atomicAdd(&RSin[b * NQ + it * 32 + srow], rsA[it]);
      #pragma unroll
      for (int it = 0; it < 2; ++it)
        atomicAdd(&RStg[b * KT + it * 32 + srow], rsB[it]);
    }
  }
}

// ---------------- stage 2 (partial mode): reduce + dice + class gather ------
__global__ __launch_bounds__(256)
void hm_stage2(const float* __restrict__ cprob, const void* __restrict__ tcls,
               const float* __restrict__ Ipart, const float* __restrict__ RSin,
               const float* __restrict__ RStg, float* __restrict__ out) {
  const int bn = blockIdx.x;            // b*NQ + n
  const int b = bn >> 7, n = bn & 127;
  const int k = threadIdx.x & 63;
  const int wq = threadIdx.x >> 6;      // 0..3
  float I = 0.f, ra = 0.f, rg = 0.f;
  #pragma unroll 4
  for (int ww = 0; ww < NW / 4; ++ww) {
    const int w = wq * (NW / 4) + ww;
    I  += Ipart[((size_t)(b * NW + w) * NQ + n) * KT + k];
    ra += RSin[(size_t)(b * NW + w) * NQ + n];
    rg += RStg[(size_t)(b * NW + w) * KT + k];
  }
  __shared__ float sI[4][64];
  __shared__ float sG[4][64];
  __shared__ float sR[4];
  sI[wq][k] = I;
  sG[wq][k] = rg;
  if (k == 0) sR[wq] = ra;
  __syncthreads();
  if (wq == 0) {
    I  = sI[0][k] + sI[1][k] + sI[2][k] + sI[3][k];
    rg = sG[0][k] + sG[1][k] + sG[2][k] + sG[3][k];
    ra = sR[0] + sR[1] + sR[2] + sR[3];
    const unsigned int hi = ((const unsigned int*)tcls)[k * 2 + 1];
    const bool i32 = (__ballot(hi != 0u) != 0ull);
    int tc = i32 ? ((const int*)tcls)[b * KT + k]
                 : (int)((const long long*)tcls)[b * KT + k];
    const float c = cprob[((size_t)b * NQ + n) * CC + tc];
    out[(size_t)bn * KT + k] = c * (2.f * I + EPSI) / (ra + rg + EPSI);
  }
}

// ---------------- stage 2 (atomic fallback mode) ----------------------------
__global__ __launch_bounds__(256)
void hm_stage2_direct(const float* __restrict__ cprob, const void* __restrict__ tcls,
                      const unsigned int* __restrict__ flag,
                      const float* __restrict__ Iacc, const float* __restrict__ RSin,
                      const float* __restrict__ RStg, float* __restrict__ out) {
  const int idx = blockIdx.x * 256 + threadIdx.x;
  const int k = idx & 63;
  const int n = (idx >> 6) & 127;
  const int b = idx >> 13;
  const float I  = Iacc[idx];
  const float ra = RSin[b * NQ + n];
  const float rg = RStg[b * KT + k];
  int tc;
  if (*flag) tc = ((const int*)tcls)[b * KT + k];
  else       tc = (int)((const long long*)tcls)[b * KT + k];
  const float c = cprob[((size_t)b * NQ + n) * CC + tc];
  out[idx] = c * (2.f * I + EPSI) / (ra + rg + EPSI);
}

__global__ void hm_zero(float* __restrict__ p, int n) {
  int i = blockIdx.x * blockDim.x + threadIdx.x;
  if (i < n) p[i] = 0.f;
}

extern "C" void kernel_launch(void* const* d_in, const int* in_sizes, int n_in,
                              void* d_out, int out_size, void* d_ws, size_t ws_size,
                              hipStream_t stream) {
  const float* cprob = (const float*)d_in[0];   // (2,128,134) f32
  const float* imask = (const float*)d_in[1];   // (2,128,65536) f32
  const float* tmask = (const float*)d_in[2];   // (2,64,65536) f32
  const void*  tcls  = d_in[3];                 // (2,64) int64 (or int32)
  float* out = (float*)d_out;                   // (2,128,64) f32

  const size_t ipart_f = (size_t)BB * NW * NQ * KT;  // 2,097,152 floats (8 MB)
  const size_t rsin_f  = (size_t)BB * NW * NQ;       // 32,768
  const size_t rstg_f  = (size_t)BB * NW * KT;       // 16,384
  const size_t need    = (ipart_f + rsin_f + rstg_f) * sizeof(float);

  char* ws = (char*)d_ws;
  if (ws_size >= need) {
    float* Ipart = (float*)ws;
    float* RSin  = Ipart + ipart_f;
    float* RStg  = RSin + rsin_f;
    hm_stage1<false><<<BB * NW, 512, 0, stream>>>(imask, tmask, Ipart, RSin, RStg);
    hm_stage2<<<BB * NQ, 256, 0, stream>>>(cprob, tcls, Ipart, RSin, RStg, out);
  } else {
    // small-scratch atomic fallback (~67 KB)
    float* Iacc = (float*)ws;                     // 16384 floats
    float* RSin = Iacc + (size_t)BB * NQ * KT;    // 256
    float* RStg = RSin + BB * NQ;                 // 128
    unsigned int* flag = (unsigned int*)(RStg + BB * KT);
    const int zn = BB * NQ * KT + BB * NQ + BB * KT;
    hm_zero<<<(zn + 255) / 256, 256, 0, stream>>>(Iacc, zn);
    hm_detect<<<1, 64, 0, stream>>>((const unsigned int*)tcls, flag);
    hm_stage1<true><<<BB * NW, 512, 0, stream>>>(imask, tmask, Iacc, RSin, RStg);
    hm_stage2_direct<<<(BB * NQ * KT) / 256, 256, 0, stream>>>(cprob, tcls, flag, Iacc, RSin, RStg, out);
  }
}